// Round 1
// baseline (744.936 us; speedup 1.0000x reference)
//
#include <hip/hip_runtime.h>
#include <cstdint>

typedef unsigned short u16;
typedef unsigned int u32;

typedef __attribute__((ext_vector_type(8))) short bf16x8;
typedef __attribute__((ext_vector_type(4))) float f32x4;

// ---- constants ----
// x: (32, 128, 112, 112) fp32 ; routing_w: (4,128) ; routing_b: (4,)
// expert_weight: (4, 256, 128, 3, 3) ; out: (32, 256, 56, 56) fp32
#define KDIM 1152      // 128*9
#define MDIM 256
#define NPIX 3136
#define NPAD 3200
#define PLANE 12544    // 112*112
#define EWSTRIDE 294912 // 256*1152 elements per expert / per sample Wmix

__device__ __forceinline__ u16 f2bf(float f) {
  u32 u = __float_as_uint(f);
  u32 r = (u + 0x7FFFu + ((u >> 16) & 1u)) >> 16;
  return (u16)r;
}

__device__ __forceinline__ void gl_lds16(const u16* g, u16* l) {
  __builtin_amdgcn_global_load_lds((__attribute__((address_space(1))) void*)g,
                                   (__attribute__((address_space(3))) void*)l,
                                   16, 0, 0);
}

// ---- 1. global average pool: pooled[b][ci] = mean(x[b,ci,:,:]) ----
__global__ __launch_bounds__(256) void pool_kernel(const float* __restrict__ x,
                                                   float* __restrict__ pooled) {
  const int ci = blockIdx.x;   // 0..127
  const int b  = blockIdx.y;   // 0..31
  const float4* p = (const float4*)(x + ((size_t)b * 128 + ci) * PLANE);
  float s = 0.f;
  for (int i = threadIdx.x; i < PLANE / 4; i += 256) {
    float4 v = p[i];
    s += v.x + v.y + v.z + v.w;
  }
  #pragma unroll
  for (int off = 32; off > 0; off >>= 1) s += __shfl_down(s, off, 64);
  __shared__ float red[4];
  if ((threadIdx.x & 63) == 0) red[threadIdx.x >> 6] = s;
  __syncthreads();
  if (threadIdx.x == 0)
    pooled[b * 128 + ci] = (red[0] + red[1] + red[2] + red[3]) * (1.0f / (float)PLANE);
}

// ---- 2. routing: rw[b][e] = sigmoid(pooled[b]·routing_w[e] + routing_b[e]) ----
__global__ void routing_kernel(const float* __restrict__ pooled,
                               const float* __restrict__ rww,
                               const float* __restrict__ rwb,
                               float* __restrict__ rw) {
  const int t = threadIdx.x;
  if (t >= 128) return;
  const int b = t >> 2, e = t & 3;
  float acc = rwb[e];
  for (int c = 0; c < 128; ++c) acc += pooled[b * 128 + c] * rww[e * 128 + c];
  rw[b * 4 + e] = 1.0f / (1.0f + expf(-acc));
}

// ---- 3. mix: Wmix[b][oc][k] = sum_e rw[b,e] * ew[e][oc][k]  (bf16 out) ----
// 36864 threads = 144 blocks x 256 ; each thread: 8 contiguous k, loops all b.
__global__ __launch_bounds__(256) void mix_kernel(const float* __restrict__ ew,
                                                  const float* __restrict__ rw,
                                                  u16* __restrict__ wmix) {
  __shared__ float srw[128];
  if (threadIdx.x < 128) srw[threadIdx.x] = rw[threadIdx.x];
  __syncthreads();
  const int t = blockIdx.x * 256 + threadIdx.x;  // < 36864
  const int idx8 = t * 8;                        // element in (oc,k) plane
  float4 e0a = *(const float4*)(ew + idx8);
  float4 e0b = *(const float4*)(ew + idx8 + 4);
  float4 e1a = *(const float4*)(ew + EWSTRIDE + idx8);
  float4 e1b = *(const float4*)(ew + EWSTRIDE + idx8 + 4);
  float4 e2a = *(const float4*)(ew + 2 * EWSTRIDE + idx8);
  float4 e2b = *(const float4*)(ew + 2 * EWSTRIDE + idx8 + 4);
  float4 e3a = *(const float4*)(ew + 3 * EWSTRIDE + idx8);
  float4 e3b = *(const float4*)(ew + 3 * EWSTRIDE + idx8 + 4);
  for (int b = 0; b < 32; ++b) {
    const float w0 = srw[b * 4 + 0], w1 = srw[b * 4 + 1];
    const float w2 = srw[b * 4 + 2], w3 = srw[b * 4 + 3];
    union { u16 o[8]; uint4 v; } pk;
    pk.o[0] = f2bf(w0 * e0a.x + w1 * e1a.x + w2 * e2a.x + w3 * e3a.x);
    pk.o[1] = f2bf(w0 * e0a.y + w1 * e1a.y + w2 * e2a.y + w3 * e3a.y);
    pk.o[2] = f2bf(w0 * e0a.z + w1 * e1a.z + w2 * e2a.z + w3 * e3a.z);
    pk.o[3] = f2bf(w0 * e0a.w + w1 * e1a.w + w2 * e2a.w + w3 * e3a.w);
    pk.o[4] = f2bf(w0 * e0b.x + w1 * e1b.x + w2 * e2b.x + w3 * e3b.x);
    pk.o[5] = f2bf(w0 * e0b.y + w1 * e1b.y + w2 * e2b.y + w3 * e3b.y);
    pk.o[6] = f2bf(w0 * e0b.z + w1 * e1b.z + w2 * e2b.z + w3 * e3b.z);
    pk.o[7] = f2bf(w0 * e0b.w + w1 * e1b.w + w2 * e2b.w + w3 * e3b.w);
    *(uint4*)(wmix + (size_t)b * EWSTRIDE + idx8) = pk.v;
  }
}

// ---- 4. im2col (per sample chunk): P[z][p][k] bf16, p in [0,3200) k in [0,1152)
// block: (oh, ci-half, z). LDS tile [56 pixels][576 k + 2 pad] ushorts.
__global__ __launch_bounds__(256) void im2col_kernel(const float* __restrict__ x,
                                                     u16* __restrict__ P, int s0) {
  __shared__ u16 tile[56 * 578];
  const int oh  = blockIdx.x;        // 0..55
  const int ci0 = blockIdx.y * 64;   // 0 or 64
  const int z   = blockIdx.z;        // local sample
  const int b   = s0 + z;
  const int lane = threadIdx.x & 63;
  const int grp  = threadIdx.x >> 6; // 0..3
  const int ow = lane;
  if (ow < 56) {
    #pragma unroll 4
    for (int i = 0; i < 16; ++i) {
      const int ci_l = grp + 4 * i;  // 0..63
      const float* xp = x + ((size_t)b * 128 + ci0 + ci_l) * PLANE;
      const int base = ow * 578 + ci_l * 9;
      #pragma unroll
      for (int kh = 0; kh < 3; ++kh) {
        const int ih = 2 * oh - 1 + kh;
        const bool rv = (ih >= 0) && (ih < 112);
        #pragma unroll
        for (int kw = 0; kw < 3; ++kw) {
          const int iw = 2 * ow - 1 + kw;
          float v = 0.f;
          if (rv && iw >= 0 && iw < 112) v = xp[ih * 112 + iw];
          tile[base + kh * 3 + kw] = f2bf(v);
        }
      }
    }
  }
  __syncthreads();
  // coalesced copy out: per pixel 288 dwords into P row (k offset ci0*9)
  u16* dbase = P + ((size_t)z * NPAD + (size_t)oh * 56) * KDIM + (size_t)blockIdx.y * 576;
  for (int pix = 0; pix < 56; ++pix) {
    const u32* src = (const u32*)&tile[pix * 578];
    u32* d = (u32*)(dbase + (size_t)pix * KDIM);
    for (int t = threadIdx.x; t < 288; t += 256) d[t] = src[t];
  }
}

// ---- 5. GEMM per sample: C[m,n] = sum_k Wmix[s][m][k] * P[z][n][k] ----
// 128x128 tile, BK=32, global_load_lds 16B staging, mfma 16x16x32 bf16.
__global__ __launch_bounds__(256) void gemm_kernel(const u16* __restrict__ Wmix,
                                                   const u16* __restrict__ Pb,
                                                   float* __restrict__ out, int s0) {
  __shared__ u16 a_sm[128 * 32];
  __shared__ u16 b_sm[128 * 32];
  const int mt = blockIdx.x, nt = blockIdx.y, z = blockIdx.z;
  const int s = s0 + z;
  const int tid = threadIdx.x;
  const int lane = tid & 63, wave = tid >> 6;
  const int srow = lane >> 2, scol = (lane & 3) * 8;
  const u16* Abase = Wmix + (size_t)s * EWSTRIDE + (size_t)mt * 128 * KDIM;
  const u16* Bbase = Pb + (size_t)z * NPAD * KDIM + (size_t)nt * 128 * KDIM;
  const u16* ga0 = Abase + (size_t)(wave * 16 + srow) * KDIM + scol;
  const u16* ga1 = ga0 + 64 * KDIM;
  const u16* gb0 = Bbase + (size_t)(wave * 16 + srow) * KDIM + scol;
  const u16* gb1 = gb0 + 64 * KDIM;
  u16* la0 = a_sm + wave * 512 + lane * 8;
  u16* la1 = la0 + 4 * 512;
  u16* lb0 = b_sm + wave * 512 + lane * 8;
  u16* lb1 = lb0 + 4 * 512;
  const int wm = wave >> 1, wn = wave & 1;
  const int fr = lane & 15, quad = lane >> 4;
  f32x4 acc[4][4];
  const f32x4 zv = {0.f, 0.f, 0.f, 0.f};
  #pragma unroll
  for (int i = 0; i < 4; ++i)
    #pragma unroll
    for (int j = 0; j < 4; ++j) acc[i][j] = zv;

  for (int kt = 0; kt < KDIM / 32; ++kt) {
    gl_lds16(ga0, la0);
    gl_lds16(ga1, la1);
    gl_lds16(gb0, lb0);
    gl_lds16(gb1, lb1);
    ga0 += 32; ga1 += 32; gb0 += 32; gb1 += 32;
    __syncthreads();
    bf16x8 av[4], bv[4];
    #pragma unroll
    for (int i = 0; i < 4; ++i)
      av[i] = *(const bf16x8*)(a_sm + (wm * 64 + i * 16 + fr) * 32 + quad * 8);
    #pragma unroll
    for (int j = 0; j < 4; ++j)
      bv[j] = *(const bf16x8*)(b_sm + (wn * 64 + j * 16 + fr) * 32 + quad * 8);
    #pragma unroll
    for (int i = 0; i < 4; ++i)
      #pragma unroll
      for (int j = 0; j < 4; ++j)
        acc[i][j] = __builtin_amdgcn_mfma_f32_16x16x32_bf16(av[i], bv[j], acc[i][j], 0, 0, 0);
    __syncthreads();
  }

  float* os = out + (size_t)s * MDIM * NPIX;
  const int mbase = mt * 128 + wm * 64 + quad * 4;
  const int nb = nt * 128 + wn * 64 + fr;
  #pragma unroll
  for (int j = 0; j < 4; ++j) {
    const int n = nb + j * 16;
    if (n < NPIX) {
      #pragma unroll
      for (int i = 0; i < 4; ++i) {
        const int m = mbase + i * 16;
        #pragma unroll
        for (int r = 0; r < 4; ++r)
          os[(size_t)(m + r) * NPIX + n] = acc[i][j][r];
      }
    }
  }
}

// ---- fallback: naive direct conv (only if ws too small) ----
__global__ __launch_bounds__(256) void naive_conv(const float* __restrict__ x,
                                                  const float* __restrict__ ew,
                                                  const float* __restrict__ rw,
                                                  float* __restrict__ out) {
  const size_t idx = (size_t)blockIdx.x * 256 + threadIdx.x;
  if (idx >= (size_t)32 * MDIM * NPIX) return;
  const int n = (int)(idx % NPIX);
  const int tmp = (int)(idx / NPIX);
  const int oc = tmp % MDIM;
  const int b = tmp / MDIM;
  const int oh = n / 56, ow = n % 56;
  const float w0 = rw[b * 4 + 0], w1 = rw[b * 4 + 1];
  const float w2 = rw[b * 4 + 2], w3 = rw[b * 4 + 3];
  float acc = 0.f;
  for (int ci = 0; ci < 128; ++ci) {
    const float* xp = x + ((size_t)b * 128 + ci) * PLANE;
    const size_t wb = ((size_t)oc * 128 + ci) * 9;
    for (int kh = 0; kh < 3; ++kh) {
      const int ih = 2 * oh - 1 + kh;
      if (ih < 0 || ih >= 112) continue;
      for (int kw = 0; kw < 3; ++kw) {
        const int iw = 2 * ow - 1 + kw;
        if (iw < 0 || iw >= 112) continue;
        const int ko = kh * 3 + kw;
        const float wv = w0 * ew[wb + ko] + w1 * ew[(size_t)EWSTRIDE * 1 * 4 / 4 + wb + ko] * 0.f; // placeholder never used
        (void)wv;
        float wsum = w0 * ew[wb + ko]
                   + w1 * ew[(size_t)1 * 4 * EWSTRIDE / 4 + wb + ko]
                   + w2 * ew[(size_t)2 * EWSTRIDE + wb + ko]
                   + w3 * ew[(size_t)3 * EWSTRIDE + wb + ko];
        acc += xp[ih * 112 + iw] * wsum;
      }
    }
  }
  out[idx] = acc;
}

extern "C" void kernel_launch(void* const* d_in, const int* in_sizes, int n_in,
                              void* d_out, int out_size, void* d_ws, size_t ws_size,
                              hipStream_t stream) {
  const float* x   = (const float*)d_in[0];
  const float* rww = (const float*)d_in[1];
  const float* rwb = (const float*)d_in[2];
  const float* ew  = (const float*)d_in[3];
  float* out = (float*)d_out;

  float* rw_ws  = (float*)d_ws;                         // 128 f
  float* pooled = (float*)((char*)d_ws + 512);          // 4096 f
  u16* wmix = (u16*)((char*)d_ws + 16896);              // 9,437,184 bf16
  u16* Pbuf = (u16*)((char*)d_ws + 16896 + 18874368);   // chunked im2col

  pool_kernel<<<dim3(128, 32), 256, 0, stream>>>(x, pooled);
  routing_kernel<<<1, 128, 0, stream>>>(pooled, rww, rwb, rw_ws);

  const size_t fixed = 16896 + 18874368ull;
  const size_t perS = (size_t)NPAD * KDIM * 2;  // 7,372,800 B
  int S = 0;
  const int cands[6] = {32, 16, 8, 4, 2, 1};
  for (int i = 0; i < 6; ++i)
    if (fixed + (size_t)cands[i] * perS <= ws_size) { S = cands[i]; break; }

  if (S > 0) {
    mix_kernel<<<144, 256, 0, stream>>>(ew, rw_ws, wmix);
    for (int g = 0; g < 32 / S; ++g) {
      im2col_kernel<<<dim3(56, 2, S), 256, 0, stream>>>(x, Pbuf, g * S);
      gemm_kernel<<<dim3(2, 25, S), 256, 0, stream>>>(wmix, Pbuf, out, g * S);
    }
  } else {
    naive_conv<<<(int)(((size_t)32 * MDIM * NPIX + 255) / 256), 256, 0, stream>>>(
        x, ew, rw_ws, out);
  }
}

// Round 2
// 741.288 us; speedup vs baseline: 1.0049x; 1.0049x over previous
//
#include <hip/hip_runtime.h>
#include <cstdint>

typedef unsigned short u16;
typedef unsigned int u32;

typedef __attribute__((ext_vector_type(8))) short bf16x8;
typedef __attribute__((ext_vector_type(4))) float f32x4;

// x: (32,128,112,112) f32 ; routing_w: (4,128) ; routing_b: (4,)
// expert_weight: (4,256,128,3,3) ; out: (32,256,56,56) f32
#define KDIM 1152       // 9*128, k = (kh*3+kw)*128 + ci  (tap-major!)
#define MDIM 256
#define NPIX 3136
#define PLANE 12544     // 112*112
#define EWSTRIDE 294912 // 256*1152
#define HH 114          // haloed spatial dim
#define XT_SAMP ((size_t)HH * HH * 128)  // u16 per sample = 1,663,488

__device__ __forceinline__ u16 f2bf(float f) {
  u32 u = __float_as_uint(f);
  return (u16)((u + 0x7FFFu + ((u >> 16) & 1u)) >> 16);
}

__device__ __forceinline__ void gl_lds16(const u16* g, u16* l) {
  __builtin_amdgcn_global_load_lds((__attribute__((address_space(1))) void*)g,
                                   (__attribute__((address_space(3))) void*)l,
                                   16, 0, 0);
}

// ---- transpose NCHW f32 -> NHWC-halo bf16, fused global-avg-pool (sums) ----
// grid (112 h, 4 = ci_half + 2*w_half, 32 b), 256 threads.
__global__ __launch_bounds__(256) void transpose_pool_kernel(
    const float* __restrict__ x, u16* __restrict__ xt, float* __restrict__ pooled) {
  __shared__ u32 tile[32][57];  // [ci_pair][w], +1 pad col
  const int h = blockIdx.x;
  const int ci_half = blockIdx.y & 1;
  const int w_half = blockIdx.y >> 1;
  const int b = blockIdx.z;
  const int lane = threadIdx.x & 63, wave = threadIdx.x >> 6;
  const float* xb = x + ((size_t)b * 128 + ci_half * 64) * PLANE + h * 112 + w_half * 56;
  #pragma unroll
  for (int i = 0; i < 8; ++i) {
    const int pr = wave + 4 * i;  // ci pair 0..31
    float va = 0.f, vb = 0.f;
    if (lane < 56) {
      va = xb[(size_t)(2 * pr) * PLANE + lane];
      vb = xb[(size_t)(2 * pr + 1) * PLANE + lane];
      tile[pr][lane] = (u32)f2bf(va) | ((u32)f2bf(vb) << 16);
    }
    float sa = va, sb = vb;
    #pragma unroll
    for (int off = 32; off > 0; off >>= 1) {
      sa += __shfl_down(sa, off, 64);
      sb += __shfl_down(sb, off, 64);
    }
    if (lane == 0) {
      atomicAdd(&pooled[b * 128 + ci_half * 64 + 2 * pr], sa);
      atomicAdd(&pooled[b * 128 + ci_half * 64 + 2 * pr + 1], sb);
    }
  }
  __syncthreads();
  // write: pixel-major, ci contiguous.  u32 view: 64 u32 per pixel.
  u32* xtb = (u32*)xt + (((size_t)b * HH + h + 1) * HH + w_half * 56 + 1) * 64 + ci_half * 32;
  #pragma unroll
  for (int it = 0; it < 7; ++it) {
    const int wl = it * 8 + wave * 2 + (lane >> 5);  // 0..55
    xtb[(size_t)wl * 64 + (lane & 31)] = tile[lane & 31][wl];
  }
}

// ---- routing: rw[b][e] = sigmoid(mean·w + b) ; pooled holds SUMS here ----
__global__ void routing_kernel(const float* __restrict__ pooled,
                               const float* __restrict__ rww,
                               const float* __restrict__ rwb,
                               float* __restrict__ rw, float scale) {
  const int t = threadIdx.x;
  if (t >= 128) return;
  const int b = t >> 2, e = t & 3;
  float acc = rwb[e];
  for (int c = 0; c < 128; ++c) acc += pooled[b * 128 + c] * scale * rww[e * 128 + c];
  rw[b * 4 + e] = 1.0f / (1.0f + expf(-acc));
}

// ---- mix: Wmix[b][oc][(kh*3+kw)*128+ci] = sum_e rw[b,e]*ew[e][oc][ci][kh,kw]
// grid (64 oc-blocks, 4 b-groups), 256 thr: thread = (oc = x*4 + t>>6, ci pair = (t&63)*2)
__global__ __launch_bounds__(256) void mix_kernel(const float* __restrict__ ew,
                                                  const float* __restrict__ rw,
                                                  u16* __restrict__ wmix) {
  const int t = threadIdx.x;
  const int oc = blockIdx.x * 4 + (t >> 6);
  const int lane = t & 63;
  const int b0 = blockIdx.y * 8;
  float ereg[4][18];  // [expert][ci_even r0..8, ci_odd r0..8]
  #pragma unroll
  for (int e = 0; e < 4; ++e) {
    const float* p = ew + ((size_t)e * 256 + oc) * 1152 + lane * 18;
    #pragma unroll
    for (int j = 0; j < 18; ++j) ereg[e][j] = p[j];
  }
  for (int bb = 0; bb < 8; ++bb) {
    const int b = b0 + bb;
    const float w0 = rw[b * 4 + 0], w1 = rw[b * 4 + 1];
    const float w2 = rw[b * 4 + 2], w3 = rw[b * 4 + 3];
    u32* dst = (u32*)(wmix + ((size_t)b * 256 + oc) * KDIM) + lane;
    #pragma unroll
    for (int r = 0; r < 9; ++r) {
      const float va = w0 * ereg[0][r] + w1 * ereg[1][r] + w2 * ereg[2][r] + w3 * ereg[3][r];
      const float vb = w0 * ereg[0][9 + r] + w1 * ereg[1][9 + r] + w2 * ereg[2][9 + r] + w3 * ereg[3][9 + r];
      dst[r * 64] = (u32)f2bf(va) | ((u32)f2bf(vb) << 16);
    }
  }
}

// ---- GEMM with implicit im2col: C[m,n] = sum_k Wmix[b][m][k] * patch[b][n][k]
// 128x128 tile, BK=32, global_load_lds 16B, mfma 16x16x32 bf16. grid (2,25,32).
__global__ __launch_bounds__(256) void gemm_kernel(const u16* __restrict__ wmix,
                                                   const u16* __restrict__ xt,
                                                   float* __restrict__ out) {
  __shared__ u16 a_sm[128 * 32];
  __shared__ u16 b_sm[128 * 32];
  const int mt = blockIdx.x, nt = blockIdx.y, b = blockIdx.z;
  const int tid = threadIdx.x, lane = tid & 63, wave = tid >> 6;
  const int srow = lane >> 2, scol = (lane & 3) * 8;
  // A staging
  const u16* ga0 = wmix + (size_t)b * EWSTRIDE + (size_t)(mt * 128 + wave * 16 + srow) * KDIM + scol;
  const u16* ga1 = ga0 + 64 * KDIM;
  u16* la0 = a_sm + wave * 512 + lane * 8;
  u16* la1 = la0 + 2048;
  // B staging: per-thread pixel bases into haloed xt (clamped; OOB pixels discarded at store)
  const u16* xtb = xt + (size_t)b * XT_SAMP;
  int p0 = nt * 128 + wave * 16 + (lane >> 2);
  int p1 = p0 + 64;
  if (p0 > NPIX - 1) p0 = NPIX - 1;
  if (p1 > NPIX - 1) p1 = NPIX - 1;
  const size_t pb0 = ((size_t)(2 * (p0 / 56)) * HH + 2 * (p0 % 56)) * 128 + scol;
  const size_t pb1 = ((size_t)(2 * (p1 / 56)) * HH + 2 * (p1 % 56)) * 128 + scol;
  u16* lb0 = b_sm + wave * 512 + lane * 8;
  u16* lb1 = lb0 + 2048;

  const int wm = wave >> 1, wn = wave & 1;
  const int fr = lane & 15, quad = lane >> 4;
  f32x4 acc[4][4];
  const f32x4 zv = {0.f, 0.f, 0.f, 0.f};
  #pragma unroll
  for (int i = 0; i < 4; ++i)
    #pragma unroll
    for (int j = 0; j < 4; ++j) acc[i][j] = zv;

  for (int kt = 0; kt < 36; ++kt) {
    const int r = kt >> 2;                 // tap 0..8
    const size_t toff = (size_t)((r / 3) * HH + (r % 3)) * 128 + (kt & 3) * 32;
    gl_lds16(ga0, la0);
    gl_lds16(ga1, la1);
    gl_lds16(xtb + pb0 + toff, lb0);
    gl_lds16(xtb + pb1 + toff, lb1);
    ga0 += 32; ga1 += 32;
    __syncthreads();
    bf16x8 av[4], bv[4];
    #pragma unroll
    for (int i = 0; i < 4; ++i)
      av[i] = *(const bf16x8*)(a_sm + (wm * 64 + i * 16 + fr) * 32 + quad * 8);
    #pragma unroll
    for (int j = 0; j < 4; ++j)
      bv[j] = *(const bf16x8*)(b_sm + (wn * 64 + j * 16 + fr) * 32 + quad * 8);
    #pragma unroll
    for (int i = 0; i < 4; ++i)
      #pragma unroll
      for (int j = 0; j < 4; ++j)
        acc[i][j] = __builtin_amdgcn_mfma_f32_16x16x32_bf16(av[i], bv[j], acc[i][j], 0, 0, 0);
    __syncthreads();
  }

  float* os = out + (size_t)b * MDIM * NPIX;
  const int mbase = mt * 128 + wm * 64 + quad * 4;
  const int nb = nt * 128 + wn * 64 + fr;
  #pragma unroll
  for (int j = 0; j < 4; ++j) {
    const int n = nb + j * 16;
    if (n < NPIX) {
      #pragma unroll
      for (int i = 0; i < 4; ++i) {
        const int m = mbase + i * 16;
        #pragma unroll
        for (int rr = 0; rr < 4; ++rr)
          os[(size_t)(m + rr) * NPIX + n] = acc[i][j][rr];
      }
    }
  }
}

// ---- fallback: pool + naive direct conv (only if ws too small) ----
__global__ __launch_bounds__(256) void pool_kernel(const float* __restrict__ x,
                                                   float* __restrict__ pooled) {
  const int ci = blockIdx.x, b = blockIdx.y;
  const float4* p = (const float4*)(x + ((size_t)b * 128 + ci) * PLANE);
  float s = 0.f;
  for (int i = threadIdx.x; i < PLANE / 4; i += 256) {
    float4 v = p[i];
    s += v.x + v.y + v.z + v.w;
  }
  #pragma unroll
  for (int off = 32; off > 0; off >>= 1) s += __shfl_down(s, off, 64);
  __shared__ float red[4];
  if ((threadIdx.x & 63) == 0) red[threadIdx.x >> 6] = s;
  __syncthreads();
  if (threadIdx.x == 0)
    pooled[b * 128 + ci] = (red[0] + red[1] + red[2] + red[3]) * (1.0f / (float)PLANE);
}

__global__ __launch_bounds__(256) void naive_conv(const float* __restrict__ x,
                                                  const float* __restrict__ ew,
                                                  const float* __restrict__ rw,
                                                  float* __restrict__ out) {
  const size_t idx = (size_t)blockIdx.x * 256 + threadIdx.x;
  if (idx >= (size_t)32 * MDIM * NPIX) return;
  const int n = (int)(idx % NPIX);
  const int tmp = (int)(idx / NPIX);
  const int oc = tmp % MDIM;
  const int b = tmp / MDIM;
  const int oh = n / 56, ow = n % 56;
  const float w0 = rw[b * 4 + 0], w1 = rw[b * 4 + 1];
  const float w2 = rw[b * 4 + 2], w3 = rw[b * 4 + 3];
  float acc = 0.f;
  for (int ci = 0; ci < 128; ++ci) {
    const float* xp = x + ((size_t)b * 128 + ci) * PLANE;
    const size_t wb = ((size_t)oc * 128 + ci) * 9;
    for (int kh = 0; kh < 3; ++kh) {
      const int ih = 2 * oh - 1 + kh;
      if (ih < 0 || ih >= 112) continue;
      for (int kw = 0; kw < 3; ++kw) {
        const int iw = 2 * ow - 1 + kw;
        if (iw < 0 || iw >= 112) continue;
        const int ko = kh * 3 + kw;
        const float wsum = w0 * ew[wb + ko] + w1 * ew[(size_t)EWSTRIDE + wb + ko]
                         + w2 * ew[2 * (size_t)EWSTRIDE + wb + ko]
                         + w3 * ew[3 * (size_t)EWSTRIDE + wb + ko];
        acc += xp[ih * 112 + iw] * wsum;
      }
    }
  }
  out[idx] = acc;
}

extern "C" void kernel_launch(void* const* d_in, const int* in_sizes, int n_in,
                              void* d_out, int out_size, void* d_ws, size_t ws_size,
                              hipStream_t stream) {
  const float* x   = (const float*)d_in[0];
  const float* rww = (const float*)d_in[1];
  const float* rwb = (const float*)d_in[2];
  const float* ew  = (const float*)d_in[3];
  float* out = (float*)d_out;

  const size_t xt_bytes = 32 * XT_SAMP * 2;            // 106,463,232
  const size_t wmix_off = xt_bytes;
  const size_t pooled_off = wmix_off + (size_t)32 * EWSTRIDE * 2;  // +18,874,368
  const size_t rw_off = pooled_off + 16384;
  const size_t need = rw_off + 512;

  if (ws_size >= need) {
    u16* xt = (u16*)d_ws;
    u16* wmix = (u16*)((char*)d_ws + wmix_off);
    float* pooled = (float*)((char*)d_ws + pooled_off);
    float* rw_ws = (float*)((char*)d_ws + rw_off);
    hipMemsetAsync(pooled, 0, 16384, stream);
    hipMemsetAsync(xt, 0, xt_bytes, stream);  // zero halo (interior overwritten)
    transpose_pool_kernel<<<dim3(112, 4, 32), 256, 0, stream>>>(x, xt, pooled);
    routing_kernel<<<1, 128, 0, stream>>>(pooled, rww, rwb, rw_ws, 1.0f / (float)PLANE);
    mix_kernel<<<dim3(64, 4), 256, 0, stream>>>(ew, rw_ws, wmix);
    gemm_kernel<<<dim3(2, 25, 32), 256, 0, stream>>>(wmix, xt, out);
  } else {
    float* pooled = (float*)d_ws;
    float* rw_ws = (float*)((char*)d_ws + 16384);
    pool_kernel<<<dim3(128, 32), 256, 0, stream>>>(x, pooled);
    routing_kernel<<<1, 128, 0, stream>>>(pooled, rww, rwb, rw_ws, 1.0f);
    naive_conv<<<(int)(((size_t)32 * MDIM * NPIX + 255) / 256), 256, 0, stream>>>(
        x, ew, rw_ws, out);
  }
}

// Round 3
// 460.060 us; speedup vs baseline: 1.6192x; 1.6113x over previous
//
#include <hip/hip_runtime.h>
#include <cstdint>

typedef unsigned short u16;
typedef unsigned int u32;

typedef __attribute__((ext_vector_type(8))) short bf16x8;
typedef __attribute__((ext_vector_type(4))) float f32x4;

// x: (32,128,112,112) f32 ; routing_w: (4,128) ; routing_b: (4,)
// expert_weight: (4,256,128,3,3) ; out: (32,256,56,56) f32
#define KDIM 1152       // 9*128, k = (kh*3+kw)*128 + ci  (tap-major)
#define MDIM 256
#define NPIX 3136
#define PLANE 12544     // 112*112
#define EWSTRIDE 294912 // 256*1152
#define HH 114          // haloed spatial dim
#define XT_SAMP ((size_t)HH * HH * 128)  // u16 per sample

__device__ __forceinline__ u16 f2bf(float f) {
  u32 u = __float_as_uint(f);
  return (u16)((u + 0x7FFFu + ((u >> 16) & 1u)) >> 16);
}

__device__ __forceinline__ void gl_lds16(const u16* g, u16* l) {
  __builtin_amdgcn_global_load_lds((__attribute__((address_space(1))) void*)g,
                                   (__attribute__((address_space(3))) void*)l,
                                   16, 0, 0);
}

// ---- halo: zero the border pixels of xt (interior written by transpose) ----
__global__ __launch_bounds__(256) void halo_kernel(u16* __restrict__ xt) {
  const int b = blockIdx.x;
  u32* xg = (u32*)xt + (size_t)b * (HH * HH * 64);
  for (int idx = threadIdx.x; idx < 452 * 64; idx += 256) {
    const int pix = idx >> 6, c = idx & 63;
    int h, w;
    if (pix < 114) { h = 0; w = pix; }
    else if (pix < 228) { h = 113; w = pix - 114; }
    else { const int q = pix - 228; h = 1 + (q >> 1); w = (q & 1) ? 113 : 0; }
    xg[((size_t)h * HH + w) * 64 + c] = 0u;
  }
}

// ---- transpose NCHW f32 -> NHWC-halo bf16, fused pool partials ----
// grid (112 h, 32 b), 256 thr. Block: all 128 ci x 112 w of one (b,h) row.
__global__ __launch_bounds__(256) void transpose_pool_kernel(
    const float* __restrict__ x, u16* __restrict__ xt, float* __restrict__ part) {
  __shared__ u32 tile[112 * 68];   // [w][ci/2], stride 68 words (16B aligned rows)
  __shared__ float psum[512];
  const int h = blockIdx.x, b = blockIdx.y;
  const int t = threadIdx.x, lane = t & 63, wave = t >> 6;
  const float* xb = x + (size_t)b * 128 * PLANE + h * 112;
  if (lane < 56) {
    #pragma unroll
    for (int wh = 0; wh < 2; ++wh) {
      const int w = wh * 56 + lane;
      #pragma unroll
      for (int i = 0; i < 4; ++i) {
        const int ci0 = (i * 4 + wave) * 8;
        const float* p = xb + (size_t)ci0 * PLANE + w;
        float v0 = p[0];
        float v1 = p[(size_t)1 * PLANE];
        float v2 = p[(size_t)2 * PLANE];
        float v3 = p[(size_t)3 * PLANE];
        float v4 = p[(size_t)4 * PLANE];
        float v5 = p[(size_t)5 * PLANE];
        float v6 = p[(size_t)6 * PLANE];
        float v7 = p[(size_t)7 * PLANE];
        uint4 d;
        d.x = (u32)f2bf(v0) | ((u32)f2bf(v1) << 16);
        d.y = (u32)f2bf(v2) | ((u32)f2bf(v3) << 16);
        d.z = (u32)f2bf(v4) | ((u32)f2bf(v5) << 16);
        d.w = (u32)f2bf(v6) | ((u32)f2bf(v7) << 16);
        *(uint4*)&tile[w * 68 + ci0 / 2] = d;
      }
    }
  }
  __syncthreads();
  // write out contiguous 112*64 u32; accumulate fp32 pool sums (thread owns ci pair)
  const int c = t & 63;
  float s0 = 0.f, s1 = 0.f;
  u32* xg = (u32*)xt + (((size_t)b * HH + h + 1) * HH + 1) * 64;
  #pragma unroll
  for (int j = 0; j < 28; ++j) {
    const int idx = t + 256 * j;
    const int w = idx >> 6;
    const u32 v = tile[w * 68 + c];
    s0 += __uint_as_float(v << 16);
    s1 += __uint_as_float(v & 0xffff0000u);
    xg[(size_t)w * 64 + c] = v;
  }
  psum[wave * 128 + 2 * c] = s0;
  psum[wave * 128 + 2 * c + 1] = s1;
  __syncthreads();
  if (t < 128)
    part[((size_t)h * 32 + b) * 128 + t] =
        psum[t] + psum[128 + t] + psum[256 + t] + psum[384 + t];
}

// ---- reduce pool partials over h ----
__global__ void reduce_pool_kernel(const float* __restrict__ part,
                                   float* __restrict__ pooled) {
  const int b = blockIdx.x, t = threadIdx.x;  // 128 threads
  float s = 0.f;
  for (int h = 0; h < 112; ++h) s += part[((size_t)h * 32 + b) * 128 + t];
  pooled[b * 128 + t] = s;
}

// ---- routing: rw[b][e] = sigmoid(mean·w + b) ; pooled holds SUMS ----
__global__ void routing_kernel(const float* __restrict__ pooled,
                               const float* __restrict__ rww,
                               const float* __restrict__ rwb,
                               float* __restrict__ rw, float scale) {
  const int t = threadIdx.x;
  if (t >= 128) return;
  const int b = t >> 2, e = t & 3;
  float acc = rwb[e];
  for (int c = 0; c < 128; ++c) acc += pooled[b * 128 + c] * scale * rww[e * 128 + c];
  rw[b * 4 + e] = 1.0f / (1.0f + expf(-acc));
}

// ---- mix: Wmix[b][oc][(kh*3+kw)*128+ci] = sum_e rw[b,e]*ew[e][oc][ci][kh,kw]
__global__ __launch_bounds__(256) void mix_kernel(const float* __restrict__ ew,
                                                  const float* __restrict__ rw,
                                                  u16* __restrict__ wmix) {
  const int t = threadIdx.x;
  const int oc = blockIdx.x * 4 + (t >> 6);
  const int lane = t & 63;
  const int b0 = blockIdx.y * 8;
  float ereg[4][18];
  #pragma unroll
  for (int e = 0; e < 4; ++e) {
    const float* p = ew + ((size_t)e * 256 + oc) * 1152 + lane * 18;
    #pragma unroll
    for (int j = 0; j < 18; ++j) ereg[e][j] = p[j];
  }
  for (int bb = 0; bb < 8; ++bb) {
    const int b = b0 + bb;
    const float w0 = rw[b * 4 + 0], w1 = rw[b * 4 + 1];
    const float w2 = rw[b * 4 + 2], w3 = rw[b * 4 + 3];
    u32* dst = (u32*)(wmix + ((size_t)b * 256 + oc) * KDIM) + lane;
    #pragma unroll
    for (int r = 0; r < 9; ++r) {
      const float va = w0 * ereg[0][r] + w1 * ereg[1][r] + w2 * ereg[2][r] + w3 * ereg[3][r];
      const float vb = w0 * ereg[0][9 + r] + w1 * ereg[1][9 + r] + w2 * ereg[2][9 + r] + w3 * ereg[3][9 + r];
      dst[r * 64] = (u32)f2bf(va) | ((u32)f2bf(vb) << 16);
    }
  }
}

// ---- GEMM with implicit im2col. grid (32 b, 50 tiles): id ≡ b (mod 8) -> XCD locality
__global__ __launch_bounds__(256) void gemm_kernel(const u16* __restrict__ wmix,
                                                   const u16* __restrict__ xt,
                                                   float* __restrict__ out) {
  __shared__ u16 a_sm[128 * 32];
  __shared__ u16 b_sm[128 * 32];
  const int b = blockIdx.x;
  const int mt = blockIdx.y & 1, nt = blockIdx.y >> 1;
  const int tid = threadIdx.x, lane = tid & 63, wave = tid >> 6;
  const int srow = lane >> 2, scol = (lane & 3) * 8;
  const u16* ga0 = wmix + (size_t)b * EWSTRIDE + (size_t)(mt * 128 + wave * 16 + srow) * KDIM + scol;
  const u16* ga1 = ga0 + 64 * KDIM;
  u16* la0 = a_sm + wave * 512 + lane * 8;
  u16* la1 = la0 + 2048;
  const u16* xtb = xt + (size_t)b * XT_SAMP;
  int p0 = nt * 128 + wave * 16 + (lane >> 2);
  int p1 = p0 + 64;
  if (p0 > NPIX - 1) p0 = NPIX - 1;
  if (p1 > NPIX - 1) p1 = NPIX - 1;
  const size_t pb0 = ((size_t)(2 * (p0 / 56)) * HH + 2 * (p0 % 56)) * 128 + scol;
  const size_t pb1 = ((size_t)(2 * (p1 / 56)) * HH + 2 * (p1 % 56)) * 128 + scol;
  u16* lb0 = b_sm + wave * 512 + lane * 8;
  u16* lb1 = lb0 + 2048;

  const int wm = wave >> 1, wn = wave & 1;
  const int fr = lane & 15, quad = lane >> 4;
  f32x4 acc[4][4];
  const f32x4 zv = {0.f, 0.f, 0.f, 0.f};
  #pragma unroll
  for (int i = 0; i < 4; ++i)
    #pragma unroll
    for (int j = 0; j < 4; ++j) acc[i][j] = zv;

  for (int kt = 0; kt < 36; ++kt) {
    const int r = kt >> 2;
    const size_t toff = (size_t)((r / 3) * HH + (r % 3)) * 128 + (kt & 3) * 32;
    gl_lds16(ga0, la0);
    gl_lds16(ga1, la1);
    gl_lds16(xtb + pb0 + toff, lb0);
    gl_lds16(xtb + pb1 + toff, lb1);
    ga0 += 32; ga1 += 32;
    __syncthreads();
    bf16x8 av[4], bv[4];
    #pragma unroll
    for (int i = 0; i < 4; ++i)
      av[i] = *(const bf16x8*)(a_sm + (wm * 64 + i * 16 + fr) * 32 + quad * 8);
    #pragma unroll
    for (int j = 0; j < 4; ++j)
      bv[j] = *(const bf16x8*)(b_sm + (wn * 64 + j * 16 + fr) * 32 + quad * 8);
    #pragma unroll
    for (int i = 0; i < 4; ++i)
      #pragma unroll
      for (int j = 0; j < 4; ++j)
        acc[i][j] = __builtin_amdgcn_mfma_f32_16x16x32_bf16(av[i], bv[j], acc[i][j], 0, 0, 0);
    __syncthreads();
  }

  float* os = out + (size_t)b * MDIM * NPIX;
  const int mbase = mt * 128 + wm * 64 + quad * 4;
  const int nb = nt * 128 + wn * 64 + fr;
  #pragma unroll
  for (int j = 0; j < 4; ++j) {
    const int n = nb + j * 16;
    if (n < NPIX) {
      #pragma unroll
      for (int i = 0; i < 4; ++i) {
        const int m = mbase + i * 16;
        #pragma unroll
        for (int rr = 0; rr < 4; ++rr)
          os[(size_t)(m + rr) * NPIX + n] = acc[i][j][rr];
      }
    }
  }
}

// ---- fallback path (ws too small): pool + naive direct conv ----
__global__ __launch_bounds__(256) void pool_kernel(const float* __restrict__ x,
                                                   float* __restrict__ pooled) {
  const int ci = blockIdx.x, b = blockIdx.y;
  const float4* p = (const float4*)(x + ((size_t)b * 128 + ci) * PLANE);
  float s = 0.f;
  for (int i = threadIdx.x; i < PLANE / 4; i += 256) {
    float4 v = p[i];
    s += v.x + v.y + v.z + v.w;
  }
  #pragma unroll
  for (int off = 32; off > 0; off >>= 1) s += __shfl_down(s, off, 64);
  __shared__ float red[4];
  if ((threadIdx.x & 63) == 0) red[threadIdx.x >> 6] = s;
  __syncthreads();
  if (threadIdx.x == 0)
    pooled[b * 128 + ci] = (red[0] + red[1] + red[2] + red[3]) * (1.0f / (float)PLANE);
}

__global__ __launch_bounds__(256) void naive_conv(const float* __restrict__ x,
                                                  const float* __restrict__ ew,
                                                  const float* __restrict__ rw,
                                                  float* __restrict__ out) {
  const size_t idx = (size_t)blockIdx.x * 256 + threadIdx.x;
  if (idx >= (size_t)32 * MDIM * NPIX) return;
  const int n = (int)(idx % NPIX);
  const int tmp = (int)(idx / NPIX);
  const int oc = tmp % MDIM;
  const int b = tmp / MDIM;
  const int oh = n / 56, ow = n % 56;
  const float w0 = rw[b * 4 + 0], w1 = rw[b * 4 + 1];
  const float w2 = rw[b * 4 + 2], w3 = rw[b * 4 + 3];
  float acc = 0.f;
  for (int ci = 0; ci < 128; ++ci) {
    const float* xp = x + ((size_t)b * 128 + ci) * PLANE;
    const size_t wb = ((size_t)oc * 128 + ci) * 9;
    for (int kh = 0; kh < 3; ++kh) {
      const int ih = 2 * oh - 1 + kh;
      if (ih < 0 || ih >= 112) continue;
      for (int kw = 0; kw < 3; ++kw) {
        const int iw = 2 * ow - 1 + kw;
        if (iw < 0 || iw >= 112) continue;
        const int ko = kh * 3 + kw;
        const float wsum = w0 * ew[wb + ko] + w1 * ew[(size_t)EWSTRIDE + wb + ko]
                         + w2 * ew[2 * (size_t)EWSTRIDE + wb + ko]
                         + w3 * ew[3 * (size_t)EWSTRIDE + wb + ko];
        acc += xp[ih * 112 + iw] * wsum;
      }
    }
  }
  out[idx] = acc;
}

extern "C" void kernel_launch(void* const* d_in, const int* in_sizes, int n_in,
                              void* d_out, int out_size, void* d_ws, size_t ws_size,
                              hipStream_t stream) {
  const float* x   = (const float*)d_in[0];
  const float* rww = (const float*)d_in[1];
  const float* rwb = (const float*)d_in[2];
  const float* ew  = (const float*)d_in[3];
  float* out = (float*)d_out;

  const size_t xt_bytes = 32 * XT_SAMP * 2;                     // 106,463,232
  const size_t wmix_off = xt_bytes;
  const size_t part_off = wmix_off + (size_t)32 * EWSTRIDE * 2; // +18,874,368
  const size_t pooled_off = part_off + (size_t)112 * 32 * 128 * 4;  // +1,835,008
  const size_t rw_off = pooled_off + 16384;
  const size_t need = rw_off + 512;

  if (ws_size >= need) {
    u16* xt = (u16*)d_ws;
    u16* wmix = (u16*)((char*)d_ws + wmix_off);
    float* part = (float*)((char*)d_ws + part_off);
    float* pooled = (float*)((char*)d_ws + pooled_off);
    float* rw_ws = (float*)((char*)d_ws + rw_off);
    halo_kernel<<<32, 256, 0, stream>>>(xt);
    transpose_pool_kernel<<<dim3(112, 32), 256, 0, stream>>>(x, xt, part);
    reduce_pool_kernel<<<32, 128, 0, stream>>>(part, pooled);
    routing_kernel<<<1, 128, 0, stream>>>(pooled, rww, rwb, rw_ws, 1.0f / (float)PLANE);
    mix_kernel<<<dim3(64, 4), 256, 0, stream>>>(ew, rw_ws, wmix);
    gemm_kernel<<<dim3(32, 50), 256, 0, stream>>>(wmix, xt, out);
  } else {
    float* pooled = (float*)d_ws;
    float* rw_ws = (float*)((char*)d_ws + 16384);
    pool_kernel<<<dim3(128, 32), 256, 0, stream>>>(x, pooled);
    routing_kernel<<<1, 128, 0, stream>>>(pooled, rww, rwb, rw_ws, 1.0f);
    naive_conv<<<(int)(((size_t)32 * MDIM * NPIX + 255) / 256), 256, 0, stream>>>(
        x, ew, rw_ws, out);
  }
}